// Round 3
// baseline (355.944 us; speedup 1.0000x reference)
//
#include <hip/hip_runtime.h>
#include <math.h>

typedef __attribute__((ext_vector_type(8))) short short8;      // 8 bf16 (4 VGPRs) MFMA operand
typedef __attribute__((ext_vector_type(4))) float floatx4;     // 16x16 MFMA accumulator
typedef __attribute__((ext_vector_type(16))) float floatx16;   // 32x32 MFMA accumulator
typedef __attribute__((ext_vector_type(8))) unsigned short ushort8v;
typedef __attribute__((ext_vector_type(4))) unsigned short ushort4v;

#define HW 4096
#define CCH 512
#define NB 4
#define NH 4
#define HD 128

__device__ __forceinline__ unsigned short f2bf(float f) {
    union { float f; unsigned int u; } c; c.f = f;
    unsigned int u = c.u;
    u += 0x7FFFu + ((u >> 16) & 1u);   // round-to-nearest-even
    return (unsigned short)(u >> 16);
}

// ---------------- weights fp32 -> bf16 ----------------
__global__ void conv_w(const float* __restrict__ w0, const float* __restrict__ w1,
                       const float* __restrict__ w2, const float* __restrict__ w3,
                       unsigned short* __restrict__ dst) {
    const float* src = blockIdx.y == 0 ? w0 : blockIdx.y == 1 ? w1 : blockIdx.y == 2 ? w2 : w3;
    unsigned short* d = dst + (size_t)blockIdx.y * 262144;
    int i = blockIdx.x * 256 + threadIdx.x;          // float4 index, 65536 total
    float4 v = ((const float4*)src)[i];
    ushort4v o;
    o[0] = f2bf(v.x); o[1] = f2bf(v.y); o[2] = f2bf(v.z); o[3] = f2bf(v.w);
    ((ushort4v*)d)[i] = o;
}

// ---------------- GroupNorm stats: one block per (b, group) ----------------
__global__ void gn_stats(const float* __restrict__ x, float* __restrict__ stats) {
    int bg = blockIdx.x;                 // 0..127
    int b = bg >> 5, g = bg & 31;
    const float4* p = (const float4*)(x + ((size_t)b * CCH + g * 16) * HW);  // 16 ch * 4096 contiguous
    float s = 0.f, ss = 0.f;
    for (int i = threadIdx.x; i < 16384; i += 256) {
        float4 v = p[i];
        s  += v.x + v.y + v.z + v.w;
        ss += v.x * v.x + v.y * v.y + v.z * v.z + v.w * v.w;
    }
    #pragma unroll
    for (int off = 32; off > 0; off >>= 1) {
        s  += __shfl_down(s, off, 64);
        ss += __shfl_down(ss, off, 64);
    }
    __shared__ float sm[4], sm2[4];
    int wid = threadIdx.x >> 6;
    if ((threadIdx.x & 63) == 0) { sm[wid] = s; sm2[wid] = ss; }
    __syncthreads();
    if (threadIdx.x == 0) {
        float ts = sm[0] + sm[1] + sm[2] + sm[3];
        float tss = sm2[0] + sm2[1] + sm2[2] + sm2[3];
        float mean = ts * (1.f / 65536.f);
        float var = tss * (1.f / 65536.f) - mean * mean;
        stats[bg * 2] = mean;
        stats[bg * 2 + 1] = rsqrtf(var + 1e-5f);
    }
}

// ---------------- normalize + transpose -> XT[b, s, c] bf16 ----------------
__global__ void gn_apply(const float* __restrict__ x, const float* __restrict__ gnw,
                         const float* __restrict__ gnb, const float* __restrict__ stats,
                         unsigned short* __restrict__ xt) {
    int s = blockIdx.x * 256 + threadIdx.x;   // 0..4095
    int g = blockIdx.y, b = blockIdx.z;
    float mean = stats[(b * 32 + g) * 2];
    float rstd = stats[(b * 32 + g) * 2 + 1];
    const float* xb = x + ((size_t)b * CCH + g * 16) * HW + s;
    unsigned short outv[16];
    #pragma unroll
    for (int cl = 0; cl < 16; cl++) {
        int c = g * 16 + cl;
        float v = xb[(size_t)cl * HW];                       // lanes->consecutive s: coalesced
        v = (v - mean) * rstd * gnw[c] + gnb[c];
        outv[cl] = f2bf(v);
    }
    unsigned short* dst = xt + ((size_t)b * HW + s) * CCH + g * 16;   // 32B contiguous per thread
    *(ushort8v*)dst       = *(ushort8v*)&outv[0];
    *(ushort8v*)(dst + 8) = *(ushort8v*)&outv[8];
}

// ---------------- NT GEMM: C[m,n] = sum_k A[m,k] B[n,k], K=512 ----------------
// MODE 0: C bf16 [m,n], bias per-col n, *scale      (Q/K projections; Q pre-scaled)
// MODE 1: C fp32 [m,n], bias per-row m, + residual  (output projection + residual)
// MODE 2: C bf16 [m,n], bias per-row m              (V projection, stored transposed)
#define LDP 72   // padded leading dim (ushorts): 72*2=144B, 16B-aligned, 36 dwords == 4 mod 32 banks
template <int MODE>
__global__ __launch_bounds__(256, 2) void gemm_nt(
    const unsigned short* __restrict__ A, long long aStride,
    const unsigned short* __restrict__ Bm, long long bStride,
    const float* __restrict__ bias, float scale,
    const float* __restrict__ resid, long long rStride,
    void* __restrict__ Cp, long long cStride, int ldc) {
    __shared__ unsigned short lA[128 * LDP];
    __shared__ unsigned short lB[128 * LDP];
    const int tid = threadIdx.x;
    const int lane = tid & 63;
    const int wid = tid >> 6;
    const int z = blockIdx.z;
    const unsigned short* Ab = A + (size_t)z * aStride + (size_t)blockIdx.x * 128 * 512;
    const unsigned short* Bb = Bm + (size_t)z * bStride + (size_t)blockIdx.y * 128 * 512;

    floatx4 acc[4][4];
    #pragma unroll
    for (int i = 0; i < 4; i++)
        #pragma unroll
        for (int j = 0; j < 4; j++) acc[i][j] = (floatx4)0.f;

    const int wm = (wid >> 1) * 64;
    const int wn = (wid & 1) * 64;
    const int l15 = lane & 15;
    const int l4 = lane >> 4;

    for (int k0 = 0; k0 < 512; k0 += 64) {
        #pragma unroll
        for (int i = 0; i < 4; i++) {
            int idx = i * 256 + tid;            // 0..1023
            int row = idx >> 3;
            int kc = (idx & 7) * 8;
            *(ushort8v*)&lA[row * LDP + kc] = *(const ushort8v*)&Ab[(size_t)row * 512 + k0 + kc];
            *(ushort8v*)&lB[row * LDP + kc] = *(const ushort8v*)&Bb[(size_t)row * 512 + k0 + kc];
        }
        __syncthreads();
        #pragma unroll
        for (int kk = 0; kk < 2; kk++) {
            short8 af[4], bf[4];
            #pragma unroll
            for (int i = 0; i < 4; i++)
                af[i] = *(const short8*)&lA[(wm + i * 16 + l15) * LDP + kk * 32 + l4 * 8];
            #pragma unroll
            for (int j = 0; j < 4; j++)
                bf[j] = *(const short8*)&lB[(wn + j * 16 + l15) * LDP + kk * 32 + l4 * 8];
            #pragma unroll
            for (int i = 0; i < 4; i++)
                #pragma unroll
                for (int j = 0; j < 4; j++)
                    acc[i][j] = __builtin_amdgcn_mfma_f32_16x16x32_bf16(af[i], bf[j], acc[i][j], 0, 0, 0);
        }
        __syncthreads();
    }

    long long m0 = (long long)blockIdx.x * 128 + wm;
    long long n0 = (long long)blockIdx.y * 128 + wn;
    if (MODE == 0) {
        unsigned short* C = (unsigned short*)Cp + (size_t)z * cStride;
        #pragma unroll
        for (int i = 0; i < 4; i++)
            #pragma unroll
            for (int j = 0; j < 4; j++) {
                long long col = n0 + j * 16 + l15;
                float bv = bias[col];
                #pragma unroll
                for (int r = 0; r < 4; r++) {
                    long long row = m0 + i * 16 + l4 * 4 + r;    // D: row=(lane>>4)*4+reg, col=lane&15
                    C[row * ldc + col] = f2bf((acc[i][j][r] + bv) * scale);
                }
            }
    } else if (MODE == 1) {
        float* C = (float*)Cp + (size_t)z * cStride;
        const float* R = resid + (size_t)z * rStride;
        #pragma unroll
        for (int i = 0; i < 4; i++)
            #pragma unroll
            for (int j = 0; j < 4; j++)
                #pragma unroll
                for (int r = 0; r < 4; r++) {
                    long long row = m0 + i * 16 + l4 * 4 + r;    // row = output channel o
                    long long col = n0 + j * 16 + l15;           // col = spatial s (coalesced)
                    C[row * ldc + col] = acc[i][j][r] + bias[row] + R[row * ldc + col];
                }
    } else {
        unsigned short* C = (unsigned short*)Cp + (size_t)z * cStride;
        #pragma unroll
        for (int i = 0; i < 4; i++)
            #pragma unroll
            for (int j = 0; j < 4; j++)
                #pragma unroll
                for (int r = 0; r < 4; r++) {
                    long long row = m0 + i * 16 + l4 * 4 + r;    // row = channel c (V^T layout)
                    long long col = n0 + j * 16 + l15;           // col = spatial s
                    C[row * ldc + col] = f2bf(acc[i][j][r] + bias[row]);
                }
    }
}

// ---------------- flash attention (no-max, 32x32 MFMA): one block per (q-tile 128, head, batch) ----------------
// Q pre-scaled by log2(e)/sqrt(hd), so p = exp2(S) directly (scores ~N(0,1): no overflow).
//
// S^T = mfma_32x32x16(K_frag, Q_frag): D gives col q = lane&31, row t = (reg&3)+8*(reg>>2)+4*(lane>>5).
// PV A-frag wants A[m=q=lane&31][k=t=tw*16+(lane>>5)*8+e] -> same q per lane; the t-halves that
// live in the partner half-wave are fetched with ONE v_permlane32_swap_b32 per cvt_pk pair:
//   w[g][0]=pk(r4g,r4g+1), w[g][1]=pk(r4g+2,r4g+3);  swap(w[2h][c], w[2h+1][c]) -> (c0,c2)/(c1,c3)
//   of A-frag tw=2tb+h (verified for both lane>>5 halves).
// V B-frag: B[n=d=dj*32+lane&31][k=t=tw*16+(lane>>5)*8+e] = CONTIGUOUS 16B of lvt[d][t] ->
//   conflict-free ds_read_b128 (replaces the half-rate b64 pairs that caused 2.5e7 bank conflicts).
// lsum: mfma(P_frag, ones) -> D rows match acc_o rows exactly; no shfl in epilogue.
//
// __launch_bounds__(256,2): peak VGPR ~200 (acc_o 64 + acc_l 16 + sa 32 + qf 32 + prefetch 32).
// (256,3) previously forced an 84-VGPR spill -- do NOT tighten; grid = 512 blocks = 2/CU anyway.
#define LQP 136   // lk stride (ushorts) = 17 x 16B slots: slot%8 = row + koff -> 2 lanes/slot, conflict-free
#define LTP 72    // lvt stride (ushorts) = 9 x 16B slots: slot%8 = row + toff -> 2 lanes/slot, conflict-free
__global__ __launch_bounds__(256, 2) void attn_kern(
    const unsigned short* __restrict__ Qb, const unsigned short* __restrict__ Kb,
    const unsigned short* __restrict__ Vt, unsigned short* __restrict__ Ob) {
    __shared__ unsigned short lk[2][64 * LQP];    // [buf][t][d]
    __shared__ unsigned short lvt[2][128 * LTP];  // [buf][d][t]
    const int tid = threadIdx.x;
    const int lane = tid & 63;
    const int w = tid >> 6;
    const int l31 = lane & 31;
    const int l1 = lane >> 5;
    const int q0 = blockIdx.x * 128;
    const int h = blockIdx.y, b = blockIdx.z;
    const size_t headOff = (size_t)h * HD;
    const size_t batchRow = (size_t)b * HW;
    const unsigned short* VtB = Vt + ((size_t)b * CCH + headOff) * HW;  // [d][s]

    // Q fragments in registers: wave w owns q-rows [w*32, w*32+32); B[n=q=l31][k=d=kd*16+l1*8+e]
    short8 qf[8];
    #pragma unroll
    for (int kd = 0; kd < 8; kd++)
        qf[kd] = *(const short8*)&Qb[(batchRow + q0 + w * 32 + l31) * 512
                                     + headOff + kd * 16 + l1 * 8];

    // all-ones B-fragment -> D[m][n] = rowsum(A[m][:])
    short8 onesf;
    #pragma unroll
    for (int e = 0; e < 8; e++) onesf[e] = (short)0x3F80;

    floatx16 acc_o[4];   // O[q][d]: col d = dj*32+l31, row q = (reg&3)+8*(reg>>2)+4*l1
    floatx16 acc_l;      // lsum[q]: same row pattern, every col identical
    acc_l = (floatx16)0.f;
    #pragma unroll
    for (int dj = 0; dj < 4; dj++) acc_o[dj] = (floatx16)0.f;

    ushort8v kreg[4], vreg[4];
    // prologue: load K/V tile 0 into regs, store to LDS buf 0
    #pragma unroll
    for (int i = 0; i < 4; i++) {
        int idx = i * 256 + tid;
        kreg[i] = *(const ushort8v*)&Kb[(batchRow + (idx >> 4)) * 512 + headOff + (idx & 15) * 8];
        vreg[i] = *(const ushort8v*)&VtB[(size_t)(idx >> 3) * HW + (idx & 7) * 8];
    }
    #pragma unroll
    for (int i = 0; i < 4; i++) {
        int idx = i * 256 + tid;
        *(ushort8v*)&lk[0][(idx >> 4) * LQP + (idx & 15) * 8] = kreg[i];
        *(ushort8v*)&lvt[0][(idx >> 3) * LTP + (idx & 7) * 8] = vreg[i];
    }
    __syncthreads();

    int cur = 0;
    for (int kt = 0; kt < 64; kt++) {
        const unsigned short* lkc  = lk[cur];
        const unsigned short* lvtc = lvt[cur];

        // prefetch next K/V tile into regs at loop TOP: latency hides under QK^T+exp+pack+PV
        if (kt < 63) {
            int t0n = (kt + 1) * 64;
            #pragma unroll
            for (int i = 0; i < 4; i++) {
                int idx = i * 256 + tid;
                kreg[i] = *(const ushort8v*)&Kb[(batchRow + t0n + (idx >> 4)) * 512 + headOff + (idx & 15) * 8];
                vreg[i] = *(const ushort8v*)&VtB[(size_t)(idx >> 3) * HW + t0n + (idx & 7) * 8];
            }
        }

        // S^T = K Q^T : sa[tb] D: row t = tb*32 + (reg&3)+8*(reg>>2)+4*l1, col q = l31
        floatx16 sa[2];
        sa[0] = (floatx16)0.f;
        sa[1] = (floatx16)0.f;
        __builtin_amdgcn_s_setprio(1);
        #pragma unroll
        for (int kd = 0; kd < 8; kd++) {
            short8 kf0 = *(const short8*)&lkc[(l31) * LQP + kd * 16 + l1 * 8];
            short8 kf1 = *(const short8*)&lkc[(32 + l31) * LQP + kd * 16 + l1 * 8];
            sa[0] = __builtin_amdgcn_mfma_f32_32x32x16_bf16(kf0, qf[kd], sa[0], 0, 0, 0);
            sa[1] = __builtin_amdgcn_mfma_f32_32x32x16_bf16(kf1, qf[kd], sa[1], 0, 0, 0);
        }
        __builtin_amdgcn_s_setprio(0);

        // p = exp2(s) in-register
        #pragma unroll
        for (int tb = 0; tb < 2; tb++)
            #pragma unroll
            for (int r = 0; r < 16; r++)
                sa[tb][r] = __builtin_amdgcn_exp2f(sa[tb][r]);

        // pack P -> PV A-frags: cvt_pk pairs + permlane32_swap to exchange l1-halves
        short8 paf[4];   // indexed by tw = 0..3
        #pragma unroll
        for (int tb = 0; tb < 2; tb++) {
            unsigned int wv[4][2];
            #pragma unroll
            for (int g = 0; g < 4; g++) {
                asm("v_cvt_pk_bf16_f32 %0, %1, %2" : "=v"(wv[g][0])
                    : "v"(sa[tb][4 * g + 0]), "v"(sa[tb][4 * g + 1]));
                asm("v_cvt_pk_bf16_f32 %0, %1, %2" : "=v"(wv[g][1])
                    : "v"(sa[tb][4 * g + 2]), "v"(sa[tb][4 * g + 3]));
            }
            #pragma unroll
            for (int hh = 0; hh < 2; hh++) {
                unsigned int a0 = wv[2 * hh][0], b0 = wv[2 * hh + 1][0];
                unsigned int a1 = wv[2 * hh][1], b1 = wv[2 * hh + 1][1];
                // D,S swap: newD = [D_lo, S_lo], newS = [D_hi, S_hi]
                asm("v_permlane32_swap_b32 %0, %1" : "+v"(a0), "+v"(b0));
                asm("v_permlane32_swap_b32 %0, %1" : "+v"(a1), "+v"(b1));
                union { unsigned int u[4]; short8 s8; } f;
                f.u[0] = a0; f.u[1] = a1; f.u[2] = b0; f.u[3] = b1;
                paf[2 * tb + hh] = f.s8;
            }
        }

        // O += P V ; lsum += rowsum(P).  V B-frag = contiguous b128 from lvt.
        __builtin_amdgcn_s_setprio(1);
        #pragma unroll
        for (int tw = 0; tw < 4; tw++) {
            acc_l = __builtin_amdgcn_mfma_f32_32x32x16_bf16(paf[tw], onesf, acc_l, 0, 0, 0);
            #pragma unroll
            for (int dj = 0; dj < 4; dj++) {
                short8 vv = *(const short8*)&lvtc[(dj * 32 + l31) * LTP + tw * 16 + l1 * 8];
                acc_o[dj] = __builtin_amdgcn_mfma_f32_32x32x16_bf16(paf[tw], vv, acc_o[dj], 0, 0, 0);
            }
        }
        __builtin_amdgcn_s_setprio(0);

        // write next tile into the OTHER buffer, ONE barrier to publish it
        if (kt < 63) {
            int nxt = cur ^ 1;
            #pragma unroll
            for (int i = 0; i < 4; i++) {
                int idx = i * 256 + tid;
                *(ushort8v*)&lk[nxt][(idx >> 4) * LQP + (idx & 15) * 8] = kreg[i];
                *(ushort8v*)&lvt[nxt][(idx >> 3) * LTP + (idx & 7) * 8] = vreg[i];
            }
            __syncthreads();
            cur = nxt;
        }
    }

    // epilogue: acc_l[reg] holds lsum for exactly the q-row acc_o[.][reg] holds
    #pragma unroll
    for (int g = 0; g < 4; g++)
        #pragma unroll
        for (int p = 0; p < 4; p++) {
            int reg = 4 * g + p;
            float rl = 1.f / acc_l[reg];
            int qr = p + 8 * g + 4 * l1;
            size_t row = batchRow + q0 + w * 32 + qr;
            #pragma unroll
            for (int dj = 0; dj < 4; dj++)
                Ob[row * 512 + headOff + dj * 32 + l31] = f2bf(acc_o[dj][reg] * rl);
        }
}

extern "C" void kernel_launch(void* const* d_in, const int* in_sizes, int n_in,
                              void* d_out, int out_size, void* d_ws, size_t ws_size,
                              hipStream_t stream) {
    const float* x   = (const float*)d_in[0];
    const float* gnw = (const float*)d_in[1];
    const float* gnb = (const float*)d_in[2];
    const float* wq  = (const float*)d_in[3];
    const float* bq  = (const float*)d_in[4];
    const float* wk  = (const float*)d_in[5];
    const float* bk  = (const float*)d_in[6];
    const float* wv  = (const float*)d_in[7];
    const float* bv  = (const float*)d_in[8];
    const float* wp  = (const float*)d_in[9];
    const float* bp  = (const float*)d_in[10];
    float* out = (float*)d_out;

    const size_t NE = (size_t)NB * HW * CCH;          // 8388608 elements
    unsigned short* ws16 = (unsigned short*)d_ws;
    unsigned short* XT = ws16;                        // x_n transposed (b,s,c); reused as attn O
    unsigned short* Qb = ws16 + NE;
    unsigned short* Kb = ws16 + 2 * NE;
    unsigned short* Vt = ws16 + 3 * NE;               // V transposed: [b][c][s]
    unsigned short* Wb = ws16 + 4 * NE;               // 4 x 262144 bf16 weights
    float* stats = (float*)(ws16 + 4 * NE + 4 * 262144);

    // fold log2(e) into the attention scale so the kernel uses exp2 directly
    const float qscale = 0.08838834764831845f * 1.4426950408889634f;

    conv_w<<<dim3(256, 4), 256, 0, stream>>>(wq, wk, wv, wp, Wb);
    gn_stats<<<128, 256, 0, stream>>>(x, stats);
    gn_apply<<<dim3(16, 32, 4), 256, 0, stream>>>(x, gnw, gnb, stats, XT);

    // Q/K: [16384 x 512] = XT @ W^T  (NT gemm, both K-contiguous); Q pre-scaled
    gemm_nt<0><<<dim3(128, 4, 1), 256, 0, stream>>>(XT, 0, Wb + 0 * 262144, 0, bq, qscale, nullptr, 0, Qb, 0, 512);
    gemm_nt<0><<<dim3(128, 4, 1), 256, 0, stream>>>(XT, 0, Wb + 1 * 262144, 0, bk, 1.f, nullptr, 0, Kb, 0, 512);
    // V stored transposed: Vt[b][c][s] = Wv @ XT[b]^T
    gemm_nt<2><<<dim3(4, 32, 4), 256, 0, stream>>>(Wb + 2 * 262144, 0, XT, (long long)HW * 512, bv, 1.f,
                                                   nullptr, 0, Vt, (long long)CCH * HW, HW);

    unsigned short* Ob = XT;   // XT dead after QKV; reuse for attention output (b,s,c)
    attn_kern<<<dim3(32, NH, NB), 256, 0, stream>>>(Qb, Kb, Vt, Ob);

    // out[b,o,s] = sum_c wp[o,c] * Ob[b,s,c] + bp[o] + x[b,o,s]
    gemm_nt<1><<<dim3(4, 32, 4), 256, 0, stream>>>(Wb + 3 * 262144, 0, Ob, (long long)HW * 512, bp, 1.f,
                                                   x, (long long)CCH * HW, out, (long long)CCH * HW, HW);
}

// Round 4
// 346.779 us; speedup vs baseline: 1.0264x; 1.0264x over previous
//
#include <hip/hip_runtime.h>
#include <math.h>

typedef __attribute__((ext_vector_type(8))) short short8;      // 8 bf16 (4 VGPRs) MFMA operand
typedef __attribute__((ext_vector_type(4))) float floatx4;     // 16x16 MFMA accumulator
typedef __attribute__((ext_vector_type(16))) float floatx16;   // 32x32 MFMA accumulator
typedef __attribute__((ext_vector_type(8))) unsigned short ushort8v;
typedef __attribute__((ext_vector_type(4))) unsigned short ushort4v;

#define HW 4096
#define CCH 512
#define NB 4
#define NH 4
#define HD 128

__device__ __forceinline__ unsigned short f2bf(float f) {
    union { float f; unsigned int u; } c; c.f = f;
    unsigned int u = c.u;
    u += 0x7FFFu + ((u >> 16) & 1u);   // round-to-nearest-even
    return (unsigned short)(u >> 16);
}

// ---------------- weights fp32 -> bf16 ----------------
__global__ void conv_w(const float* __restrict__ w0, const float* __restrict__ w1,
                       const float* __restrict__ w2, const float* __restrict__ w3,
                       unsigned short* __restrict__ dst) {
    const float* src = blockIdx.y == 0 ? w0 : blockIdx.y == 1 ? w1 : blockIdx.y == 2 ? w2 : w3;
    unsigned short* d = dst + (size_t)blockIdx.y * 262144;
    int i = blockIdx.x * 256 + threadIdx.x;          // float4 index, 65536 total
    float4 v = ((const float4*)src)[i];
    ushort4v o;
    o[0] = f2bf(v.x); o[1] = f2bf(v.y); o[2] = f2bf(v.z); o[3] = f2bf(v.w);
    ((ushort4v*)d)[i] = o;
}

// ---------------- GroupNorm stats: one block per (b, group) ----------------
__global__ void gn_stats(const float* __restrict__ x, float* __restrict__ stats) {
    int bg = blockIdx.x;                 // 0..127
    int b = bg >> 5, g = bg & 31;
    const float4* p = (const float4*)(x + ((size_t)b * CCH + g * 16) * HW);  // 16 ch * 4096 contiguous
    float s = 0.f, ss = 0.f;
    for (int i = threadIdx.x; i < 16384; i += 256) {
        float4 v = p[i];
        s  += v.x + v.y + v.z + v.w;
        ss += v.x * v.x + v.y * v.y + v.z * v.z + v.w * v.w;
    }
    #pragma unroll
    for (int off = 32; off > 0; off >>= 1) {
        s  += __shfl_down(s, off, 64);
        ss += __shfl_down(ss, off, 64);
    }
    __shared__ float sm[4], sm2[4];
    int wid = threadIdx.x >> 6;
    if ((threadIdx.x & 63) == 0) { sm[wid] = s; sm2[wid] = ss; }
    __syncthreads();
    if (threadIdx.x == 0) {
        float ts = sm[0] + sm[1] + sm[2] + sm[3];
        float tss = sm2[0] + sm2[1] + sm2[2] + sm2[3];
        float mean = ts * (1.f / 65536.f);
        float var = tss * (1.f / 65536.f) - mean * mean;
        stats[bg * 2] = mean;
        stats[bg * 2 + 1] = rsqrtf(var + 1e-5f);
    }
}

// ---------------- normalize + transpose -> XT[b, s, c] bf16 ----------------
__global__ void gn_apply(const float* __restrict__ x, const float* __restrict__ gnw,
                         const float* __restrict__ gnb, const float* __restrict__ stats,
                         unsigned short* __restrict__ xt) {
    int s = blockIdx.x * 256 + threadIdx.x;   // 0..4095
    int g = blockIdx.y, b = blockIdx.z;
    float mean = stats[(b * 32 + g) * 2];
    float rstd = stats[(b * 32 + g) * 2 + 1];
    const float* xb = x + ((size_t)b * CCH + g * 16) * HW + s;
    unsigned short outv[16];
    #pragma unroll
    for (int cl = 0; cl < 16; cl++) {
        int c = g * 16 + cl;
        float v = xb[(size_t)cl * HW];                       // lanes->consecutive s: coalesced
        v = (v - mean) * rstd * gnw[c] + gnb[c];
        outv[cl] = f2bf(v);
    }
    unsigned short* dst = xt + ((size_t)b * HW + s) * CCH + g * 16;   // 32B contiguous per thread
    *(ushort8v*)dst       = *(ushort8v*)&outv[0];
    *(ushort8v*)(dst + 8) = *(ushort8v*)&outv[8];
}

// ---------------- NT GEMM: C[m,n] = sum_k A[m,k] B[n,k], K=512 ----------------
// MODE 0: C bf16 [m,n], bias per-col n, *scale      (single projection)
// MODE 1: C fp32 [m,n], bias per-row m, + residual  (output projection + residual)
// MODE 2: C bf16 [m,n], bias per-row m              (V projection, stored transposed)
// MODE 3: like MODE 0 but dual-launch over z: z=0 -> (bias, scale); z=1 -> (resid-as-bias, 1.0)
//         with B and C strided by z (Q and K projections fused into one dispatch).
// Reg-prefetch + LDS double-buffer: ONE barrier per K-step, global latency hidden under MFMA.
#define LDP 72   // padded leading dim (ushorts): 72*2=144B, 16B-aligned, 36 dwords == 4 mod 32 banks
template <int MODE>
__global__ __launch_bounds__(256, 2) void gemm_nt(
    const unsigned short* __restrict__ A, long long aStride,
    const unsigned short* __restrict__ Bm, long long bStride,
    const float* __restrict__ bias, float scale,
    const float* __restrict__ resid, long long rStride,
    void* __restrict__ Cp, long long cStride, int ldc) {
    __shared__ unsigned short lA[2][128 * LDP];
    __shared__ unsigned short lB[2][128 * LDP];
    const int tid = threadIdx.x;
    const int lane = tid & 63;
    const int wid = tid >> 6;
    const int z = blockIdx.z;
    const unsigned short* Ab = A + (size_t)z * aStride + (size_t)blockIdx.x * 128 * 512;
    const unsigned short* Bb = Bm + (size_t)z * bStride + (size_t)blockIdx.y * 128 * 512;

    floatx4 acc[4][4];
    #pragma unroll
    for (int i = 0; i < 4; i++)
        #pragma unroll
        for (int j = 0; j < 4; j++) acc[i][j] = (floatx4)0.f;

    const int wm = (wid >> 1) * 64;
    const int wn = (wid & 1) * 64;
    const int l15 = lane & 15;
    const int l4 = lane >> 4;
    const int srow = tid >> 3;            // 0..31 base row block (idx>>3 for i=0)
    const int skc  = (tid & 7) * 8;       // k-chunk within 64

    ushort8v ar[4], br[4];
    // prologue: tile 0 -> regs -> LDS buf 0
    #pragma unroll
    for (int i = 0; i < 4; i++) {
        int row = srow + i * 32;
        ar[i] = *(const ushort8v*)&Ab[(size_t)row * 512 + skc];
        br[i] = *(const ushort8v*)&Bb[(size_t)row * 512 + skc];
    }
    #pragma unroll
    for (int i = 0; i < 4; i++) {
        int row = srow + i * 32;
        *(ushort8v*)&lA[0][row * LDP + skc] = ar[i];
        *(ushort8v*)&lB[0][row * LDP + skc] = br[i];
    }
    __syncthreads();

    int cur = 0;
    #pragma unroll 1
    for (int t = 0; t < 8; t++) {
        // prefetch next K-tile into regs (latency hides under the MFMAs below)
        if (t < 7) {
            int k0 = (t + 1) * 64;
            #pragma unroll
            for (int i = 0; i < 4; i++) {
                int row = srow + i * 32;
                ar[i] = *(const ushort8v*)&Ab[(size_t)row * 512 + k0 + skc];
                br[i] = *(const ushort8v*)&Bb[(size_t)row * 512 + k0 + skc];
            }
        }
        #pragma unroll
        for (int kk = 0; kk < 2; kk++) {
            short8 af[4], bf[4];
            #pragma unroll
            for (int i = 0; i < 4; i++)
                af[i] = *(const short8*)&lA[cur][(wm + i * 16 + l15) * LDP + kk * 32 + l4 * 8];
            #pragma unroll
            for (int j = 0; j < 4; j++)
                bf[j] = *(const short8*)&lB[cur][(wn + j * 16 + l15) * LDP + kk * 32 + l4 * 8];
            #pragma unroll
            for (int i = 0; i < 4; i++)
                #pragma unroll
                for (int j = 0; j < 4; j++)
                    acc[i][j] = __builtin_amdgcn_mfma_f32_16x16x32_bf16(af[i], bf[j], acc[i][j], 0, 0, 0);
        }
        if (t < 7) {
            int nxt = cur ^ 1;
            #pragma unroll
            for (int i = 0; i < 4; i++) {
                int row = srow + i * 32;
                *(ushort8v*)&lA[nxt][row * LDP + skc] = ar[i];
                *(ushort8v*)&lB[nxt][row * LDP + skc] = br[i];
            }
            __syncthreads();
            cur = nxt;
        }
    }

    long long m0 = (long long)blockIdx.x * 128 + wm;
    long long n0 = (long long)blockIdx.y * 128 + wn;
    if (MODE == 0 || MODE == 3) {
        unsigned short* C = (unsigned short*)Cp + (size_t)z * cStride;
        const float* bptr = (MODE == 3 && z == 1) ? resid : bias;
        float sc = (MODE == 3 && z == 1) ? 1.f : scale;
        #pragma unroll
        for (int i = 0; i < 4; i++)
            #pragma unroll
            for (int j = 0; j < 4; j++) {
                long long col = n0 + j * 16 + l15;
                float bv = bptr[col];
                #pragma unroll
                for (int r = 0; r < 4; r++) {
                    long long row = m0 + i * 16 + l4 * 4 + r;    // D: row=(lane>>4)*4+reg, col=lane&15
                    C[row * ldc + col] = f2bf((acc[i][j][r] + bv) * sc);
                }
            }
    } else if (MODE == 1) {
        float* C = (float*)Cp + (size_t)z * cStride;
        const float* R = resid + (size_t)z * rStride;
        #pragma unroll
        for (int i = 0; i < 4; i++)
            #pragma unroll
            for (int j = 0; j < 4; j++)
                #pragma unroll
                for (int r = 0; r < 4; r++) {
                    long long row = m0 + i * 16 + l4 * 4 + r;    // row = output channel o
                    long long col = n0 + j * 16 + l15;           // col = spatial s (coalesced)
                    C[row * ldc + col] = acc[i][j][r] + bias[row] + R[row * ldc + col];
                }
    } else {
        unsigned short* C = (unsigned short*)Cp + (size_t)z * cStride;
        #pragma unroll
        for (int i = 0; i < 4; i++)
            #pragma unroll
            for (int j = 0; j < 4; j++)
                #pragma unroll
                for (int r = 0; r < 4; r++) {
                    long long row = m0 + i * 16 + l4 * 4 + r;    // row = channel c (V^T layout)
                    long long col = n0 + j * 16 + l15;           // col = spatial s
                    C[row * ldc + col] = f2bf(acc[i][j][r] + bias[row]);
                }
    }
}

// ---------------- flash attention (no-max, 32x32 MFMA): one block per (q-tile 128, head, batch) ----------------
// Q pre-scaled by log2(e)/sqrt(hd), so p = exp2(S) directly (scores ~N(0,1): no overflow).
//
// S^T = mfma_32x32x16(K_frag, Q_frag): D gives col q = lane&31, row t = (reg&3)+8*(reg>>2)+4*(lane>>5).
// PV A-frag wants A[m=q=lane&31][k=t=tw*16+(lane>>5)*8+e] -> same q per lane; the t-halves that
// live in the partner half-wave are fetched with ONE v_permlane32_swap_b32 per cvt_pk pair.
// V B-frag: B[n=d=dj*32+lane&31][k=t] = CONTIGUOUS 16B of lvt[d][t] -> conflict-free ds_read_b128.
// lsum: mfma(P_frag, ones) -> D rows match acc_o rows exactly; no shfl in epilogue.
//
// SOFTWARE PIPELINE (this round): softmax is split per tb-half and issued in the MFMA shadow:
//   QK(tb0+tb1) -> pack(tb0) [sa1 mfmas still in flight] -> PV tw0/1 -> pack(tb1) [executes
//   under the in-flight PV mfmas] -> PV tw2/3.  Keeps the matrix pipe busy through the
//   exp2/cvt/permlane phases instead of idling ~600 cyc/kt (MfmaUtil 46% -> target ~55%).
//
// __launch_bounds__(256,2): peak VGPR ~190. (256,3) previously forced an 84-VGPR spill --
// do NOT tighten; grid = 512 blocks = 2/CU anyway.
#define LQP 136   // lk stride (ushorts) = 17 x 16B slots: slot%8 = row + koff -> 2 lanes/slot, conflict-free
#define LTP 72    // lvt stride (ushorts) = 9 x 16B slots: slot%8 = row + toff -> 2 lanes/slot, conflict-free
__global__ __launch_bounds__(256, 2) void attn_kern(
    const unsigned short* __restrict__ Qb, const unsigned short* __restrict__ Kb,
    const unsigned short* __restrict__ Vt, unsigned short* __restrict__ Ob) {
    __shared__ unsigned short lk[2][64 * LQP];    // [buf][t][d]
    __shared__ unsigned short lvt[2][128 * LTP];  // [buf][d][t]
    const int tid = threadIdx.x;
    const int lane = tid & 63;
    const int w = tid >> 6;
    const int l31 = lane & 31;
    const int l1 = lane >> 5;
    const int q0 = blockIdx.x * 128;
    const int h = blockIdx.y, b = blockIdx.z;
    const size_t headOff = (size_t)h * HD;
    const size_t batchRow = (size_t)b * HW;
    const unsigned short* VtB = Vt + ((size_t)b * CCH + headOff) * HW;  // [d][s]

    // Q fragments in registers: wave w owns q-rows [w*32, w*32+32); B[n=q=l31][k=d=kd*16+l1*8+e]
    short8 qf[8];
    #pragma unroll
    for (int kd = 0; kd < 8; kd++)
        qf[kd] = *(const short8*)&Qb[(batchRow + q0 + w * 32 + l31) * 512
                                     + headOff + kd * 16 + l1 * 8];

    // all-ones B-fragment -> D[m][n] = rowsum(A[m][:])
    short8 onesf;
    #pragma unroll
    for (int e = 0; e < 8; e++) onesf[e] = (short)0x3F80;

    floatx16 acc_o[4];   // O[q][d]: col d = dj*32+l31, row q = (reg&3)+8*(reg>>2)+4*l1
    floatx16 acc_l;      // lsum[q]: same row pattern, every col identical
    acc_l = (floatx16)0.f;
    #pragma unroll
    for (int dj = 0; dj < 4; dj++) acc_o[dj] = (floatx16)0.f;

    ushort8v kreg[4], vreg[4];
    // prologue: load K/V tile 0 into regs, store to LDS buf 0
    #pragma unroll
    for (int i = 0; i < 4; i++) {
        int idx = i * 256 + tid;
        kreg[i] = *(const ushort8v*)&Kb[(batchRow + (idx >> 4)) * 512 + headOff + (idx & 15) * 8];
        vreg[i] = *(const ushort8v*)&VtB[(size_t)(idx >> 3) * HW + (idx & 7) * 8];
    }
    #pragma unroll
    for (int i = 0; i < 4; i++) {
        int idx = i * 256 + tid;
        *(ushort8v*)&lk[0][(idx >> 4) * LQP + (idx & 15) * 8] = kreg[i];
        *(ushort8v*)&lvt[0][(idx >> 3) * LTP + (idx & 7) * 8] = vreg[i];
    }
    __syncthreads();

    int cur = 0;
    for (int kt = 0; kt < 64; kt++) {
        const unsigned short* lkc  = lk[cur];
        const unsigned short* lvtc = lvt[cur];

        // prefetch next K/V tile into regs at loop TOP: latency hides under QK^T+softmax+PV
        if (kt < 63) {
            int t0n = (kt + 1) * 64;
            #pragma unroll
            for (int i = 0; i < 4; i++) {
                int idx = i * 256 + tid;
                kreg[i] = *(const ushort8v*)&Kb[(batchRow + t0n + (idx >> 4)) * 512 + headOff + (idx & 15) * 8];
                vreg[i] = *(const ushort8v*)&VtB[(size_t)(idx >> 3) * HW + t0n + (idx & 7) * 8];
            }
        }

        // S^T = K Q^T : sa[tb] D: row t = tb*32 + (reg&3)+8*(reg>>2)+4*l1, col q = l31
        floatx16 sa0 = (floatx16)0.f;
        floatx16 sa1 = (floatx16)0.f;
        __builtin_amdgcn_s_setprio(1);
        #pragma unroll
        for (int kd = 0; kd < 8; kd++) {
            short8 kf0 = *(const short8*)&lkc[(l31) * LQP + kd * 16 + l1 * 8];
            short8 kf1 = *(const short8*)&lkc[(32 + l31) * LQP + kd * 16 + l1 * 8];
            sa0 = __builtin_amdgcn_mfma_f32_32x32x16_bf16(kf0, qf[kd], sa0, 0, 0, 0);
            sa1 = __builtin_amdgcn_mfma_f32_32x32x16_bf16(kf1, qf[kd], sa1, 0, 0, 0);
        }
        __builtin_amdgcn_s_setprio(0);

        // ---- pack tb0 (sa1's MFMAs still in flight keep the matrix pipe busy) ----
        short8 paf0, paf1;
        {
            #pragma unroll
            for (int r = 0; r < 16; r++) sa0[r] = __builtin_amdgcn_exp2f(sa0[r]);
            unsigned int wv[4][2];
            #pragma unroll
            for (int g = 0; g < 4; g++) {
                asm("v_cvt_pk_bf16_f32 %0, %1, %2" : "=v"(wv[g][0])
                    : "v"(sa0[4 * g + 0]), "v"(sa0[4 * g + 1]));
                asm("v_cvt_pk_bf16_f32 %0, %1, %2" : "=v"(wv[g][1])
                    : "v"(sa0[4 * g + 2]), "v"(sa0[4 * g + 3]));
            }
            unsigned int a0 = wv[0][0], b0 = wv[1][0], a1 = wv[0][1], b1 = wv[1][1];
            asm("v_permlane32_swap_b32 %0, %1" : "+v"(a0), "+v"(b0));
            asm("v_permlane32_swap_b32 %0, %1" : "+v"(a1), "+v"(b1));
            union { unsigned int u[4]; short8 s8; } f0;
            f0.u[0] = a0; f0.u[1] = a1; f0.u[2] = b0; f0.u[3] = b1;
            paf0 = f0.s8;
            unsigned int c0 = wv[2][0], d0 = wv[3][0], c1 = wv[2][1], d1 = wv[3][1];
            asm("v_permlane32_swap_b32 %0, %1" : "+v"(c0), "+v"(d0));
            asm("v_permlane32_swap_b32 %0, %1" : "+v"(c1), "+v"(d1));
            union { unsigned int u[4]; short8 s8; } f1;
            f1.u[0] = c0; f1.u[1] = c1; f1.u[2] = d0; f1.u[3] = d1;
            paf1 = f1.s8;
        }

        // ---- PV tw0/1 (tb0) ----
        __builtin_amdgcn_s_setprio(1);
        acc_l = __builtin_amdgcn_mfma_f32_32x32x16_bf16(paf0, onesf, acc_l, 0, 0, 0);
        #pragma unroll
        for (int dj = 0; dj < 4; dj++) {
            short8 vv = *(const short8*)&lvtc[(dj * 32 + l31) * LTP + 0 * 16 + l1 * 8];
            acc_o[dj] = __builtin_amdgcn_mfma_f32_32x32x16_bf16(paf0, vv, acc_o[dj], 0, 0, 0);
        }
        acc_l = __builtin_amdgcn_mfma_f32_32x32x16_bf16(paf1, onesf, acc_l, 0, 0, 0);
        #pragma unroll
        for (int dj = 0; dj < 4; dj++) {
            short8 vv = *(const short8*)&lvtc[(dj * 32 + l31) * LTP + 1 * 16 + l1 * 8];
            acc_o[dj] = __builtin_amdgcn_mfma_f32_32x32x16_bf16(paf1, vv, acc_o[dj], 0, 0, 0);
        }
        __builtin_amdgcn_s_setprio(0);

        // ---- pack tb1 (executes under the in-flight PV tw0/1 MFMAs) ----
        short8 paf2, paf3;
        {
            #pragma unroll
            for (int r = 0; r < 16; r++) sa1[r] = __builtin_amdgcn_exp2f(sa1[r]);
            unsigned int wv[4][2];
            #pragma unroll
            for (int g = 0; g < 4; g++) {
                asm("v_cvt_pk_bf16_f32 %0, %1, %2" : "=v"(wv[g][0])
                    : "v"(sa1[4 * g + 0]), "v"(sa1[4 * g + 1]));
                asm("v_cvt_pk_bf16_f32 %0, %1, %2" : "=v"(wv[g][1])
                    : "v"(sa1[4 * g + 2]), "v"(sa1[4 * g + 3]));
            }
            unsigned int a0 = wv[0][0], b0 = wv[1][0], a1 = wv[0][1], b1 = wv[1][1];
            asm("v_permlane32_swap_b32 %0, %1" : "+v"(a0), "+v"(b0));
            asm("v_permlane32_swap_b32 %0, %1" : "+v"(a1), "+v"(b1));
            union { unsigned int u[4]; short8 s8; } f2;
            f2.u[0] = a0; f2.u[1] = a1; f2.u[2] = b0; f2.u[3] = b1;
            paf2 = f2.s8;
            unsigned int c0 = wv[2][0], d0 = wv[3][0], c1 = wv[2][1], d1 = wv[3][1];
            asm("v_permlane32_swap_b32 %0, %1" : "+v"(c0), "+v"(d0));
            asm("v_permlane32_swap_b32 %0, %1" : "+v"(c1), "+v"(d1));
            union { unsigned int u[4]; short8 s8; } f3;
            f3.u[0] = c0; f3.u[1] = c1; f3.u[2] = d0; f3.u[3] = d1;
            paf3 = f3.s8;
        }

        // ---- PV tw2/3 (tb1) ----
        __builtin_amdgcn_s_setprio(1);
        acc_l = __builtin_amdgcn_mfma_f32_32x32x16_bf16(paf2, onesf, acc_l, 0, 0, 0);
        #pragma unroll
        for (int dj = 0; dj < 4; dj++) {
            short8 vv = *(const short8*)&lvtc[(dj * 32 + l31) * LTP + 2 * 16 + l1 * 8];
            acc_o[dj] = __builtin_amdgcn_mfma_f32_32x32x16_bf16(paf2, vv, acc_o[dj], 0, 0, 0);
        }
        acc_l = __builtin_amdgcn_mfma_f32_32x32x16_bf16(paf3, onesf, acc_l, 0, 0, 0);
        #pragma unroll
        for (int dj = 0; dj < 4; dj++) {
            short8 vv = *(const short8*)&lvtc[(dj * 32 + l31) * LTP + 3 * 16 + l1 * 8];
            acc_o[dj] = __builtin_amdgcn_mfma_f32_32x32x16_bf16(paf3, vv, acc_o[dj], 0, 0, 0);
        }
        __builtin_amdgcn_s_setprio(0);

        // write next tile into the OTHER buffer, ONE barrier to publish it
        if (kt < 63) {
            int nxt = cur ^ 1;
            #pragma unroll
            for (int i = 0; i < 4; i++) {
                int idx = i * 256 + tid;
                *(ushort8v*)&lk[nxt][(idx >> 4) * LQP + (idx & 15) * 8] = kreg[i];
                *(ushort8v*)&lvt[nxt][(idx >> 3) * LTP + (idx & 7) * 8] = vreg[i];
            }
            __syncthreads();
            cur = nxt;
        }
    }

    // epilogue: acc_l[reg] holds lsum for exactly the q-row acc_o[.][reg] holds
    #pragma unroll
    for (int g = 0; g < 4; g++)
        #pragma unroll
        for (int p = 0; p < 4; p++) {
            int reg = 4 * g + p;
            float rl = 1.f / acc_l[reg];
            int qr = p + 8 * g + 4 * l1;
            size_t row = batchRow + q0 + w * 32 + qr;
            #pragma unroll
            for (int dj = 0; dj < 4; dj++)
                Ob[row * 512 + headOff + dj * 32 + l31] = f2bf(acc_o[dj][reg] * rl);
        }
}

extern "C" void kernel_launch(void* const* d_in, const int* in_sizes, int n_in,
                              void* d_out, int out_size, void* d_ws, size_t ws_size,
                              hipStream_t stream) {
    const float* x   = (const float*)d_in[0];
    const float* gnw = (const float*)d_in[1];
    const float* gnb = (const float*)d_in[2];
    const float* wq  = (const float*)d_in[3];
    const float* bq  = (const float*)d_in[4];
    const float* wk  = (const float*)d_in[5];
    const float* bk  = (const float*)d_in[6];
    const float* wv  = (const float*)d_in[7];
    const float* bv  = (const float*)d_in[8];
    const float* wp  = (const float*)d_in[9];
    const float* bp  = (const float*)d_in[10];
    float* out = (float*)d_out;

    const size_t NE = (size_t)NB * HW * CCH;          // 8388608 elements
    unsigned short* ws16 = (unsigned short*)d_ws;
    unsigned short* XT = ws16;                        // x_n transposed (b,s,c); reused as attn O
    unsigned short* Qb = ws16 + NE;
    unsigned short* Kb = ws16 + 2 * NE;
    unsigned short* Vt = ws16 + 3 * NE;               // V transposed: [b][c][s]
    unsigned short* Wb = ws16 + 4 * NE;               // 4 x 262144 bf16 weights
    float* stats = (float*)(ws16 + 4 * NE + 4 * 262144);

    // fold log2(e) into the attention scale so the kernel uses exp2 directly
    const float qscale = 0.08838834764831845f * 1.4426950408889634f;

    conv_w<<<dim3(256, 4), 256, 0, stream>>>(wq, wk, wv, wp, Wb);
    gn_stats<<<128, 256, 0, stream>>>(x, stats);
    gn_apply<<<dim3(16, 32, 4), 256, 0, stream>>>(x, gnw, gnb, stats, XT);

    // Q and K projections fused into one dispatch: z=0 -> Q (bias bq, *qscale), z=1 -> K (bias bk)
    gemm_nt<3><<<dim3(128, 4, 2), 256, 0, stream>>>(XT, 0, Wb, 262144, bq, qscale, bk, 0,
                                                    Qb, (long long)NE, 512);
    // V stored transposed: Vt[b][c][s] = Wv @ XT[b]^T
    gemm_nt<2><<<dim3(4, 32, 4), 256, 0, stream>>>(Wb + 2 * 262144, 0, XT, (long long)HW * 512, bv, 1.f,
                                                   nullptr, 0, Vt, (long long)CCH * HW, HW);

    unsigned short* Ob = XT;   // XT dead after QKV; reuse for attention output (b,s,c)
    attn_kern<<<dim3(32, NH, NB), 256, 0, stream>>>(Qb, Kb, Vt, Ob);

    // out[b,o,s] = sum_c wp[o,c] * Ob[b,s,c] + bp[o] + x[b,o,s]
    gemm_nt<1><<<dim3(4, 32, 4), 256, 0, stream>>>(Wb + 3 * 262144, 0, Ob, (long long)HW * 512, bp, 1.f,
                                                   x, (long long)CCH * HW, out, (long long)CCH * HW, HW);
}

// Round 5
// 332.775 us; speedup vs baseline: 1.0696x; 1.0421x over previous
//
#include <hip/hip_runtime.h>
#include <math.h>

typedef __attribute__((ext_vector_type(8))) short short8;      // 8 bf16 (4 VGPRs) MFMA operand
typedef __attribute__((ext_vector_type(4))) float floatx4;     // 16x16 MFMA accumulator
typedef __attribute__((ext_vector_type(16))) float floatx16;   // 32x32 MFMA accumulator
typedef __attribute__((ext_vector_type(8))) unsigned short ushort8v;
typedef __attribute__((ext_vector_type(4))) unsigned short ushort4v;

#define HW 4096
#define CCH 512
#define NB 4
#define NH 4
#define HD 128

__device__ __forceinline__ unsigned short f2bf(float f) {
    union { float f; unsigned int u; } c; c.f = f;
    unsigned int u = c.u;
    u += 0x7FFFu + ((u >> 16) & 1u);   // round-to-nearest-even
    return (unsigned short)(u >> 16);
}

// async global->LDS DMA, 16B per lane. LDS dest = wave-uniform base + lane*16 (linear);
// swizzled layouts are achieved by permuting the per-lane GLOBAL source address.
__device__ __forceinline__ void gload_lds16(const unsigned short* g, unsigned short* l) {
    __builtin_amdgcn_global_load_lds(
        (const __attribute__((address_space(1))) unsigned int*)g,
        (__attribute__((address_space(3))) unsigned int*)l, 16, 0, 0);
}

// ---------------- weights fp32 -> bf16 ----------------
__global__ void conv_w(const float* __restrict__ w0, const float* __restrict__ w1,
                       const float* __restrict__ w2, const float* __restrict__ w3,
                       unsigned short* __restrict__ dst) {
    const float* src = blockIdx.y == 0 ? w0 : blockIdx.y == 1 ? w1 : blockIdx.y == 2 ? w2 : w3;
    unsigned short* d = dst + (size_t)blockIdx.y * 262144;
    int i = blockIdx.x * 256 + threadIdx.x;          // float4 index, 65536 total
    float4 v = ((const float4*)src)[i];
    ushort4v o;
    o[0] = f2bf(v.x); o[1] = f2bf(v.y); o[2] = f2bf(v.z); o[3] = f2bf(v.w);
    ((ushort4v*)d)[i] = o;
}

// ---------------- GroupNorm stats: one block per (b, group) ----------------
__global__ void gn_stats(const float* __restrict__ x, float* __restrict__ stats) {
    int bg = blockIdx.x;                 // 0..127
    int b = bg >> 5, g = bg & 31;
    const float4* p = (const float4*)(x + ((size_t)b * CCH + g * 16) * HW);  // 16 ch * 4096 contiguous
    float s = 0.f, ss = 0.f;
    for (int i = threadIdx.x; i < 16384; i += 256) {
        float4 v = p[i];
        s  += v.x + v.y + v.z + v.w;
        ss += v.x * v.x + v.y * v.y + v.z * v.z + v.w * v.w;
    }
    #pragma unroll
    for (int off = 32; off > 0; off >>= 1) {
        s  += __shfl_down(s, off, 64);
        ss += __shfl_down(ss, off, 64);
    }
    __shared__ float sm[4], sm2[4];
    int wid = threadIdx.x >> 6;
    if ((threadIdx.x & 63) == 0) { sm[wid] = s; sm2[wid] = ss; }
    __syncthreads();
    if (threadIdx.x == 0) {
        float ts = sm[0] + sm[1] + sm[2] + sm[3];
        float tss = sm2[0] + sm2[1] + sm2[2] + sm2[3];
        float mean = ts * (1.f / 65536.f);
        float var = tss * (1.f / 65536.f) - mean * mean;
        stats[bg * 2] = mean;
        stats[bg * 2 + 1] = rsqrtf(var + 1e-5f);
    }
}

// ---------------- normalize + transpose -> XT[b, s, c] bf16 ----------------
__global__ void gn_apply(const float* __restrict__ x, const float* __restrict__ gnw,
                         const float* __restrict__ gnb, const float* __restrict__ stats,
                         unsigned short* __restrict__ xt) {
    int s = blockIdx.x * 256 + threadIdx.x;   // 0..4095
    int g = blockIdx.y, b = blockIdx.z;
    float mean = stats[(b * 32 + g) * 2];
    float rstd = stats[(b * 32 + g) * 2 + 1];
    const float* xb = x + ((size_t)b * CCH + g * 16) * HW + s;
    unsigned short outv[16];
    #pragma unroll
    for (int cl = 0; cl < 16; cl++) {
        int c = g * 16 + cl;
        float v = xb[(size_t)cl * HW];                       // lanes->consecutive s: coalesced
        v = (v - mean) * rstd * gnw[c] + gnb[c];
        outv[cl] = f2bf(v);
    }
    unsigned short* dst = xt + ((size_t)b * HW + s) * CCH + g * 16;   // 32B contiguous per thread
    *(ushort8v*)dst       = *(ushort8v*)&outv[0];
    *(ushort8v*)(dst + 8) = *(ushort8v*)&outv[8];
}

// ---------------- NT GEMM: C[m,n] = sum_k A[m,k] B[n,k], K=512 ----------------
// MODE 0: C bf16 [m,n], bias per-col n, *scale      (single projection)
// MODE 1: C fp32 [m,n], bias per-row m, + residual  (output projection + residual)
// MODE 2: C bf16 [m,n], bias per-row m              (V projection, stored transposed)
// MODE 3: like MODE 0 but dual-launch over z: z=0 -> (bias, scale); z=1 -> (resid-as-bias, 1.0)
//         with B and C strided by z (Q and K projections fused into one dispatch).
// Reg-prefetch + LDS double-buffer: ONE barrier per K-step, global latency hidden under MFMA.
#define LDP 72   // padded leading dim (ushorts): 72*2=144B, 16B-aligned, 36 dwords == 4 mod 32 banks
template <int MODE>
__global__ __launch_bounds__(256, 2) void gemm_nt(
    const unsigned short* __restrict__ A, long long aStride,
    const unsigned short* __restrict__ Bm, long long bStride,
    const float* __restrict__ bias, float scale,
    const float* __restrict__ resid, long long rStride,
    void* __restrict__ Cp, long long cStride, int ldc) {
    __shared__ unsigned short lA[2][128 * LDP];
    __shared__ unsigned short lB[2][128 * LDP];
    const int tid = threadIdx.x;
    const int lane = tid & 63;
    const int wid = tid >> 6;
    const int z = blockIdx.z;
    const unsigned short* Ab = A + (size_t)z * aStride + (size_t)blockIdx.x * 128 * 512;
    const unsigned short* Bb = Bm + (size_t)z * bStride + (size_t)blockIdx.y * 128 * 512;

    floatx4 acc[4][4];
    #pragma unroll
    for (int i = 0; i < 4; i++)
        #pragma unroll
        for (int j = 0; j < 4; j++) acc[i][j] = (floatx4)0.f;

    const int wm = (wid >> 1) * 64;
    const int wn = (wid & 1) * 64;
    const int l15 = lane & 15;
    const int l4 = lane >> 4;
    const int srow = tid >> 3;            // 0..31 base row block (idx>>3 for i=0)
    const int skc  = (tid & 7) * 8;       // k-chunk within 64

    ushort8v ar[4], br[4];
    // prologue: tile 0 -> regs -> LDS buf 0
    #pragma unroll
    for (int i = 0; i < 4; i++) {
        int row = srow + i * 32;
        ar[i] = *(const ushort8v*)&Ab[(size_t)row * 512 + skc];
        br[i] = *(const ushort8v*)&Bb[(size_t)row * 512 + skc];
    }
    #pragma unroll
    for (int i = 0; i < 4; i++) {
        int row = srow + i * 32;
        *(ushort8v*)&lA[0][row * LDP + skc] = ar[i];
        *(ushort8v*)&lB[0][row * LDP + skc] = br[i];
    }
    __syncthreads();

    int cur = 0;
    #pragma unroll 1
    for (int t = 0; t < 8; t++) {
        // prefetch next K-tile into regs (latency hides under the MFMAs below)
        if (t < 7) {
            int k0 = (t + 1) * 64;
            #pragma unroll
            for (int i = 0; i < 4; i++) {
                int row = srow + i * 32;
                ar[i] = *(const ushort8v*)&Ab[(size_t)row * 512 + k0 + skc];
                br[i] = *(const ushort8v*)&Bb[(size_t)row * 512 + k0 + skc];
            }
        }
        #pragma unroll
        for (int kk = 0; kk < 2; kk++) {
            short8 af[4], bf[4];
            #pragma unroll
            for (int i = 0; i < 4; i++)
                af[i] = *(const short8*)&lA[cur][(wm + i * 16 + l15) * LDP + kk * 32 + l4 * 8];
            #pragma unroll
            for (int j = 0; j < 4; j++)
                bf[j] = *(const short8*)&lB[cur][(wn + j * 16 + l15) * LDP + kk * 32 + l4 * 8];
            #pragma unroll
            for (int i = 0; i < 4; i++)
                #pragma unroll
                for (int j = 0; j < 4; j++)
                    acc[i][j] = __builtin_amdgcn_mfma_f32_16x16x32_bf16(af[i], bf[j], acc[i][j], 0, 0, 0);
        }
        if (t < 7) {
            int nxt = cur ^ 1;
            #pragma unroll
            for (int i = 0; i < 4; i++) {
                int row = srow + i * 32;
                *(ushort8v*)&lA[nxt][row * LDP + skc] = ar[i];
                *(ushort8v*)&lB[nxt][row * LDP + skc] = br[i];
            }
            __syncthreads();
            cur = nxt;
        }
    }

    long long m0 = (long long)blockIdx.x * 128 + wm;
    long long n0 = (long long)blockIdx.y * 128 + wn;
    if (MODE == 0 || MODE == 3) {
        unsigned short* C = (unsigned short*)Cp + (size_t)z * cStride;
        const float* bptr = (MODE == 3 && z == 1) ? resid : bias;
        float sc = (MODE == 3 && z == 1) ? 1.f : scale;
        #pragma unroll
        for (int i = 0; i < 4; i++)
            #pragma unroll
            for (int j = 0; j < 4; j++) {
                long long col = n0 + j * 16 + l15;
                float bv = bptr[col];
                #pragma unroll
                for (int r = 0; r < 4; r++) {
                    long long row = m0 + i * 16 + l4 * 4 + r;    // D: row=(lane>>4)*4+reg, col=lane&15
                    C[row * ldc + col] = f2bf((acc[i][j][r] + bv) * sc);
                }
            }
    } else if (MODE == 1) {
        float* C = (float*)Cp + (size_t)z * cStride;
        const float* R = resid + (size_t)z * rStride;
        #pragma unroll
        for (int i = 0; i < 4; i++)
            #pragma unroll
            for (int j = 0; j < 4; j++)
                #pragma unroll
                for (int r = 0; r < 4; r++) {
                    long long row = m0 + i * 16 + l4 * 4 + r;    // row = output channel o
                    long long col = n0 + j * 16 + l15;           // col = spatial s (coalesced)
                    C[row * ldc + col] = acc[i][j][r] + bias[row] + R[row * ldc + col];
                }
    } else {
        unsigned short* C = (unsigned short*)Cp + (size_t)z * cStride;
        #pragma unroll
        for (int i = 0; i < 4; i++)
            #pragma unroll
            for (int j = 0; j < 4; j++)
                #pragma unroll
                for (int r = 0; r < 4; r++) {
                    long long row = m0 + i * 16 + l4 * 4 + r;    // row = channel c (V^T layout)
                    long long col = n0 + j * 16 + l15;           // col = spatial s
                    C[row * ldc + col] = f2bf(acc[i][j][r] + bias[row]);
                }
    }
}

// ---------------- flash attention (no-max, 32x32 MFMA, DMA-staged, PV||QK fused) ----------------
// One block per (q-tile 128, head, batch). Q pre-scaled by log2(e)/sqrt(hd) -> p = exp2(S).
//
// Staging via global_load_lds (async DMA): linear LDS dest, XOR-swizzled per-lane GLOBAL source.
//   K: lk[64][128] linear-by-slot; element (row,c) at slot row*16 + (c ^ s_k(row)),
//      s_k(row) = ((row&7)<<1) | ((row>>3)&1).  Read residues: 8 x 4 lanes, conflict-free.
//   V: lvt[128][64]; element (d,c) at slot d*8 + (c ^ (d&7)).  Read residues: 8 x 8, conflict-free.
// Pipeline (1 barrier/kt): K consumed one iter AHEAD of V ->
//   iter kt: [DMA V(kt+1)->lvNxt, DMA K(kt+2)->kWrite] [pack(kt)] [PV(kt, lvCur) || QK(kt+1, kRead)]
//            [barrier] [swap]
//   Hazards: DMA targets were fully consumed >=1 barrier ago; barrier (vmcnt drain) publishes.
// The fused 36-MFMA cluster has no VALU inside -> matrix pipe stays fed; DMA removes all
// ds_write + staging-VGPR cost.
__global__ __launch_bounds__(256, 2) void attn_kern(
    const unsigned short* __restrict__ Qb, const unsigned short* __restrict__ Kb,
    const unsigned short* __restrict__ Vt, unsigned short* __restrict__ Ob) {
    __shared__ __align__(16) unsigned short lk0[8192], lk1[8192];   // K tiles [64 rows][128 d] (swizzled slots)
    __shared__ __align__(16) unsigned short lv0[8192], lv1[8192];   // V tiles [128 d][64 t]   (swizzled slots)
    const int tid = threadIdx.x;
    const int lane = tid & 63;
    const int w = tid >> 6;
    const int l31 = lane & 31;
    const int l1 = lane >> 5;
    const int q0 = blockIdx.x * 128;
    const int h = blockIdx.y, b = blockIdx.z;
    const size_t headOff = (size_t)h * HD;
    const size_t batchRow = (size_t)b * HW;
    const unsigned short* VtB = Vt + ((size_t)b * CCH + headOff) * HW;  // [d][s]

    // per-thread DMA source indices (ushort units); advance by t0 each iter
    size_t kSrc[4], vSrc[4];
    #pragma unroll
    for (int n = 0; n < 4; n++) {
        int row = w * 16 + n * 4 + (lane >> 4);
        int sk = ((row & 7) << 1) | ((row >> 3) & 1);
        int jk = (lane & 15) ^ sk;
        kSrc[n] = (batchRow + row) * 512 + headOff + jk * 8;
        int d = w * 32 + n * 8 + (lane >> 3);
        int jv = (lane & 7) ^ (d & 7);
        vSrc[n] = (size_t)d * HW + jv * 8;
    }
    const int ldsOff = w * 4 * 512;   // wave-uniform LDS chunk base (ushorts); +n*512 per load

    // read-side swizzle constants
    const int sk0 = ((l31 & 7) << 1) | ((l31 >> 3) & 1);
    const int sv0 = l31 & 7;

    // Q fragments in registers: wave w owns q-rows [w*32, w*32+32); B[n=q=l31][k=d=kd*16+l1*8+e]
    short8 qf[8];
    #pragma unroll
    for (int kd = 0; kd < 8; kd++)
        qf[kd] = *(const short8*)&Qb[(batchRow + q0 + w * 32 + l31) * 512
                                     + headOff + kd * 16 + l1 * 8];

    // all-ones B-fragment -> D[m][n] = rowsum(A[m][:])
    short8 onesf;
    #pragma unroll
    for (int e = 0; e < 8; e++) onesf[e] = (short)0x3F80;

    floatx16 acc_o[4];   // O[q][d]: col d = dj*32+l31, row q = (reg&3)+8*(reg>>2)+4*l1
    floatx16 acc_l;      // lsum[q]: same row pattern, every col identical
    acc_l = (floatx16)0.f;
    #pragma unroll
    for (int dj = 0; dj < 4; dj++) acc_o[dj] = (floatx16)0.f;

    // prologue: DMA K(0)->lk0, K(1)->lk1, V(0)->lv0; publish; QK(0); publish-consumption barrier
    #pragma unroll
    for (int n = 0; n < 4; n++) gload_lds16(&Kb[kSrc[n]], lk0 + ldsOff + n * 512);
    #pragma unroll
    for (int n = 0; n < 4; n++) gload_lds16(&Kb[kSrc[n] + (size_t)64 * 512], lk1 + ldsOff + n * 512);
    #pragma unroll
    for (int n = 0; n < 4; n++) gload_lds16(&VtB[vSrc[n]], lv0 + ldsOff + n * 512);
    __syncthreads();

    floatx16 sa0 = (floatx16)0.f, sa1 = (floatx16)0.f;
    #pragma unroll
    for (int kd = 0; kd < 8; kd++) {
        int xk = ((kd * 2 + l1) ^ sk0) * 8;
        short8 kf0 = *(const short8*)&lk0[l31 * 128 + xk];
        short8 kf1 = *(const short8*)&lk0[l31 * 128 + xk + 4096];
        sa0 = __builtin_amdgcn_mfma_f32_32x32x16_bf16(kf0, qf[kd], sa0, 0, 0, 0);
        sa1 = __builtin_amdgcn_mfma_f32_32x32x16_bf16(kf1, qf[kd], sa1, 0, 0, 0);
    }
    __syncthreads();   // all waves done reading lk0 before iter 0's DMA K(2)->lk0

    unsigned short* lvCur = lv0;  unsigned short* lvNxt = lv1;
    unsigned short* kRead = lk1;  unsigned short* kWrite = lk0;

    #pragma unroll 1
    for (int kt = 0; kt < 63; kt++) {
        // issue async DMA: V(kt+1) -> lvNxt, K(kt+2) -> kWrite (targets consumed >=1 barrier ago;
        // kt=62's K(64) reads harmless in-workspace bytes and is never consumed)
        {
            size_t tv = (size_t)(kt + 1) * 64;
            size_t tk = (size_t)(kt + 2) * 64 * 512;
            #pragma unroll
            for (int n = 0; n < 4; n++) gload_lds16(&VtB[vSrc[n] + tv], lvNxt + ldsOff + n * 512);
            #pragma unroll
            for (int n = 0; n < 4; n++) gload_lds16(&Kb[kSrc[n] + tk], kWrite + ldsOff + n * 512);
        }

        // ---- pack(kt): p = exp2(S) in-register, cvt_pk pairs + permlane32_swap -> paf[0..3] ----
        short8 paf[4];
        #pragma unroll
        for (int r = 0; r < 16; r++) sa0[r] = __builtin_amdgcn_exp2f(sa0[r]);
        #pragma unroll
        for (int r = 0; r < 16; r++) sa1[r] = __builtin_amdgcn_exp2f(sa1[r]);
        #pragma unroll
        for (int tb = 0; tb < 2; tb++) {
            const floatx16& sa = tb ? sa1 : sa0;
            unsigned int wv[4][2];
            #pragma unroll
            for (int g = 0; g < 4; g++) {
                asm("v_cvt_pk_bf16_f32 %0, %1, %2" : "=v"(wv[g][0])
                    : "v"(sa[4 * g + 0]), "v"(sa[4 * g + 1]));
                asm("v_cvt_pk_bf16_f32 %0, %1, %2" : "=v"(wv[g][1])
                    : "v"(sa[4 * g + 2]), "v"(sa[4 * g + 3]));
            }
            #pragma unroll
            for (int hh = 0; hh < 2; hh++) {
                unsigned int a0 = wv[2 * hh][0], b0 = wv[2 * hh + 1][0];
                unsigned int a1 = wv[2 * hh][1], b1 = wv[2 * hh + 1][1];
                asm("v_permlane32_swap_b32 %0, %1" : "+v"(a0), "+v"(b0));
                asm("v_permlane32_swap_b32 %0, %1" : "+v"(a1), "+v"(b1));
                union { unsigned int u[4]; short8 s8; } f;
                f.u[0] = a0; f.u[1] = a1; f.u[2] = b0; f.u[3] = b1;
                paf[2 * tb + hh] = f.s8;
            }
        }

        // ---- fused MFMA cluster: PV(kt) from lvCur  ||  QK(kt+1) from kRead ----
        sa0 = (floatx16)0.f; sa1 = (floatx16)0.f;
        __builtin_amdgcn_s_setprio(1);
        #pragma unroll
        for (int u = 0; u < 4; u++) {
            #pragma unroll
            for (int q2 = 0; q2 < 2; q2++) {
                int kd = u * 2 + q2;
                int xk = ((kd * 2 + l1) ^ sk0) * 8;
                short8 kf0 = *(const short8*)&kRead[l31 * 128 + xk];
                short8 kf1 = *(const short8*)&kRead[l31 * 128 + xk + 4096];
                sa0 = __builtin_amdgcn_mfma_f32_32x32x16_bf16(kf0, qf[kd], sa0, 0, 0, 0);
                sa1 = __builtin_amdgcn_mfma_f32_32x32x16_bf16(kf1, qf[kd], sa1, 0, 0, 0);
            }
            acc_l = __builtin_amdgcn_mfma_f32_32x32x16_bf16(paf[u], onesf, acc_l, 0, 0, 0);
            int xv = ((u * 2 + l1) ^ sv0) * 8;
            #pragma unroll
            for (int dj = 0; dj < 4; dj++) {
                short8 vv = *(const short8*)&lvCur[dj * 2048 + l31 * 64 + xv];
                acc_o[dj] = __builtin_amdgcn_mfma_f32_32x32x16_bf16(paf[u], vv, acc_o[dj], 0, 0, 0);
            }
        }
        __builtin_amdgcn_s_setprio(0);

        __syncthreads();   // drains this wave's DMA (vmcnt) + publishes tiles V(kt+1), K(kt+2)
        unsigned short* t;
        t = lvCur; lvCur = lvNxt; lvNxt = t;
        t = kRead; kRead = kWrite; kWrite = t;
    }

    // ---- tail kt=63: pack + PV only ----
    {
        short8 paf[4];
        #pragma unroll
        for (int r = 0; r < 16; r++) sa0[r] = __builtin_amdgcn_exp2f(sa0[r]);
        #pragma unroll
        for (int r = 0; r < 16; r++) sa1[r] = __builtin_amdgcn_exp2f(sa1[r]);
        #pragma unroll
        for (int tb = 0; tb < 2; tb++) {
            const floatx16& sa = tb ? sa1 : sa0;
            unsigned int wv[4][2];
            #pragma unroll
            for (int g = 0; g < 4; g++) {
                asm("v_cvt_pk_bf16_f32 %0, %1, %2" : "=v"(wv[g][0])
                    : "v"(sa[4 * g + 0]), "v"(sa[4 * g + 1]));
                asm("v_cvt_pk_bf16_f32 %0, %1, %2" : "=v"(wv[g][1])
                    : "v"(sa[4 * g + 2]), "v"(sa[4 * g + 3]));
            }
            #pragma unroll
            for (int hh = 0; hh < 2; hh++) {
                unsigned int a0 = wv[2 * hh][0], b0 = wv[2 * hh + 1][0];
                unsigned int a1 = wv[2 * hh][1], b1 = wv[2 * hh + 1][1];
                asm("v_permlane32_swap_b32 %0, %1" : "+v"(a0), "+v"(b0));
                asm("v_permlane32_swap_b32 %0, %1" : "+v"(a1), "+v"(b1));
                union { unsigned int u[4]; short8 s8; } f;
                f.u[0] = a0; f.u[1] = a1; f.u[2] = b0; f.u[3] = b1;
                paf[2 * tb + hh] = f.s8;
            }
        }
        __builtin_amdgcn_s_setprio(1);
        #pragma unroll
        for (int u = 0; u < 4; u++) {
            acc_l = __builtin_amdgcn_mfma_f32_32x32x16_bf16(paf[u], onesf, acc_l, 0, 0, 0);
            int xv = ((u * 2 + l1) ^ sv0) * 8;
            #pragma unroll
            for (int dj = 0; dj < 4; dj++) {
                short8 vv = *(const short8*)&lvCur[dj * 2048 + l31 * 64 + xv];
                acc_o[dj] = __builtin_amdgcn_mfma_f32_32x32x16_bf16(paf[u], vv, acc_o[dj], 0, 0, 0);
            }
        }
        __builtin_amdgcn_s_setprio(0);
    }

    // epilogue: acc_l[reg] holds lsum for exactly the q-row acc_o[.][reg] holds
    #pragma unroll
    for (int g = 0; g < 4; g++)
        #pragma unroll
        for (int p = 0; p < 4; p++) {
            int reg = 4 * g + p;
            float rl = 1.f / acc_l[reg];
            int qr = p + 8 * g + 4 * l1;
            size_t row = batchRow + q0 + w * 32 + qr;
            #pragma unroll
            for (int dj = 0; dj < 4; dj++)
                Ob[row * 512 + headOff + dj * 32 + l31] = f2bf(acc_o[dj][reg] * rl);
        }
}

extern "C" void kernel_launch(void* const* d_in, const int* in_sizes, int n_in,
                              void* d_out, int out_size, void* d_ws, size_t ws_size,
                              hipStream_t stream) {
    const float* x   = (const float*)d_in[0];
    const float* gnw = (const float*)d_in[1];
    const float* gnb = (const float*)d_in[2];
    const float* wq  = (const float*)d_in[3];
    const float* bq  = (const float*)d_in[4];
    const float* wk  = (const float*)d_in[5];
    const float* bk  = (const float*)d_in[6];
    const float* wv  = (const float*)d_in[7];
    const float* bv  = (const float*)d_in[8];
    const float* wp  = (const float*)d_in[9];
    const float* bp  = (const float*)d_in[10];
    float* out = (float*)d_out;

    const size_t NE = (size_t)NB * HW * CCH;          // 8388608 elements
    unsigned short* ws16 = (unsigned short*)d_ws;
    unsigned short* XT = ws16;                        // x_n transposed (b,s,c); reused as attn O
    unsigned short* Qb = ws16 + NE;
    unsigned short* Kb = ws16 + 2 * NE;
    unsigned short* Vt = ws16 + 3 * NE;               // V transposed: [b][c][s]
    unsigned short* Wb = ws16 + 4 * NE;               // 4 x 262144 bf16 weights
    float* stats = (float*)(ws16 + 4 * NE + 4 * 262144);

    // fold log2(e) into the attention scale so the kernel uses exp2 directly
    const float qscale = 0.08838834764831845f * 1.4426950408889634f;

    conv_w<<<dim3(256, 4), 256, 0, stream>>>(wq, wk, wv, wp, Wb);
    gn_stats<<<128, 256, 0, stream>>>(x, stats);
    gn_apply<<<dim3(16, 32, 4), 256, 0, stream>>>(x, gnw, gnb, stats, XT);

    // Q and K projections fused into one dispatch: z=0 -> Q (bias bq, *qscale), z=1 -> K (bias bk)
    gemm_nt<3><<<dim3(128, 4, 2), 256, 0, stream>>>(XT, 0, Wb, 262144, bq, qscale, bk, 0,
                                                    Qb, (long long)NE, 512);
    // V stored transposed: Vt[b][c][s] = Wv @ XT[b]^T
    gemm_nt<2><<<dim3(4, 32, 4), 256, 0, stream>>>(Wb + 2 * 262144, 0, XT, (long long)HW * 512, bv, 1.f,
                                                   nullptr, 0, Vt, (long long)CCH * HW, HW);

    unsigned short* Ob = XT;   // XT dead after QKV; reuse for attention output (b,s,c)
    attn_kern<<<dim3(32, NH, NB), 256, 0, stream>>>(Qb, Kb, Vt, Ob);

    // out[b,o,s] = sum_c wp[o,c] * Ob[b,s,c] + bp[o] + x[b,o,s]
    gemm_nt<1><<<dim3(4, 32, 4), 256, 0, stream>>>(Wb + 3 * 262144, 0, Ob, (long long)HW * 512, bp, 1.f,
                                                   x, (long long)CCH * HW, out, (long long)CCH * HW, HW);
}